// Round 9
// baseline (776.925 us; speedup 1.0000x reference)
//
#include <hip/hip_runtime.h>
#include <hip/hip_bf16.h>
#include <cmath>

#define DEVFN __device__ __forceinline__

typedef __attribute__((ext_vector_type(8))) short short8;
typedef __attribute__((ext_vector_type(4))) float f32x4;

constexpr int C_DIM   = 1024;
constexpr int E_NUM   = 8;
constexpr int DFF_DIM = 4096;
constexpr int NTOK    = 8192;       // B*T
constexpr int PAD     = 256;        // expert segment alignment
constexpr int MAXROWS = NTOK * 2 + E_NUM * PAD;  // 18432

DEVFN unsigned short f2bf(float f) {
    __hip_bfloat16 h = __float2bfloat16(f);
    return __builtin_bit_cast(unsigned short, h);
}
DEVFN void gload_lds16(const void* g, void* lds) {
    __builtin_amdgcn_global_load_lds(
        (const __attribute__((address_space(1))) unsigned int*)g,
        (__attribute__((address_space(3))) unsigned int*)lds, 16, 0, 0);
}

// meta layout (ints): [0..7] counts, [8..15] cursor, [16..24] offs (offs[8]=padTotal)

__global__ void init_kernel(int* meta, int* rowtok) {
    int gid = blockIdx.x * 256 + threadIdx.x;
    if (gid < 64) meta[gid] = 0;
    if (gid < MAXROWS) rowtok[gid] = 0;
}

// One-time: wg[c][e], wn[c][e] -> wT[o][c] (o<8: gate, o>=8: noise). 16K elems.
__global__ void wrouter_T_kernel(const float* __restrict__ wg, const float* __restrict__ wn,
                                 float* __restrict__ wT) {
    int i = blockIdx.x * 256 + threadIdx.x;  // 16384
    int o = i >> 10, c = i & 1023;
    wT[i] = (o < 8) ? wg[c * 8 + o] : wn[c * 8 + (o - 8)];
}

// Router: 32 tokens/block, 8 threads/token. Coalesced x float4 loads,
// broadcast wT loads, fp64 accumulation (exact products, fp64 adds).
__global__ __launch_bounds__(256) void router_kernel(
    const float* __restrict__ x, const float* __restrict__ noise,
    const float* __restrict__ wT, const float* __restrict__ bg,
    const float* __restrict__ bn, int* meta, int2* tok_e, float2* tok_w) {
    int tid = threadIdx.x;
    int tt = tid >> 3, sub = tid & 7;
    int tok = blockIdx.x * 32 + tt;
    const float* xr = x + (size_t)tok * C_DIM;

    double acc[16];
#pragma unroll
    for (int o = 0; o < 16; o++) acc[o] = 0.0;

#pragma unroll 4
    for (int i = 0; i < 32; i++) {
        int c = i * 32 + sub * 4;
        float4 xv = *(const float4*)(xr + c);
#pragma unroll
        for (int o = 0; o < 16; o++) {
            float4 wv = *(const float4*)(wT + o * C_DIM + c);
            acc[o] += (double)xv.x * (double)wv.x;
            acc[o] += (double)xv.y * (double)wv.y;
            acc[o] += (double)xv.z * (double)wv.z;
            acc[o] += (double)xv.w * (double)wv.w;
        }
    }
#pragma unroll
    for (int s = 1; s <= 4; s <<= 1) {
#pragma unroll
        for (int o = 0; o < 16; o++) acc[o] += __shfl_xor(acc[o], s, 64);
    }
    if (sub == 0) {
        double logit[8];
#pragma unroll
        for (int e = 0; e < 8; e++) {
            double cl = acc[e] + (double)bg[e];
            double nl = acc[8 + e] + (double)bn[e];
            double sp = (nl > 30.0) ? nl : log1p(exp(nl));
            logit[e] = cl + (double)noise[(size_t)tok * 8 + e] * sp;
        }
        int i1 = -1, i2 = -1;
        double v1 = -1e300, v2 = -1e300;
#pragma unroll
        for (int e = 0; e < 8; e++) {
            double v = logit[e];
            if (v > v1) { v2 = v1; i2 = i1; v1 = v; i1 = e; }
            else if (v > v2) { v2 = v; i2 = e; }
        }
        double d = exp(v2 - v1);
        tok_e[tok] = make_int2(i1, i2);
        tok_w[tok] = make_float2((float)(1.0 / (1.0 + d)), (float)(d / (1.0 + d)));
        atomicAdd(&meta[i1], 1);
        atomicAdd(&meta[i2], 1);
    }
}

__global__ void offsets_kernel(int* meta) {
    if (threadIdx.x == 0 && blockIdx.x == 0) {
        int off = 0;
        for (int e = 0; e < 8; e++) {
            meta[16 + e] = off;
            off += (meta[e] + PAD - 1) / PAD * PAD;
            meta[8 + e] = 0;  // cursor
        }
        meta[24] = off;  // padTotal
    }
}

// Wave-aggregated slot assignment (atomic order doesn't affect any FP result).
__global__ void assign_kernel(int* meta, const int2* tok_e,
                              int2* tok_pos, int* rowtok) {
    int t = blockIdx.x * 256 + threadIdx.x;
    int lane = threadIdx.x & 63;
    int2 e = tok_e[t];
    int sel[2] = {e.x, e.y};
    int pos[2];
#pragma unroll
    for (int s = 0; s < 2; s++) {
        int p = 0;
#pragma unroll
        for (int ex = 0; ex < 8; ex++) {
            unsigned long long m = __ballot(sel[s] == ex);
            if (m) {
                int leader = __ffsll((unsigned long long)m) - 1;
                int base = 0;
                if (lane == leader) base = atomicAdd(&meta[8 + ex], (int)__popcll(m));
                base = __shfl(base, leader, 64);
                if (sel[s] == ex)
                    p = meta[16 + ex] + base + (int)__popcll(m & ((1ull << lane) - 1ull));
            }
        }
        pos[s] = p;
        rowtok[p] = t;
    }
    tok_pos[t] = make_int2(pos[0], pos[1]);
}

// Gather token rows into packed order, fp32 -> bf16.
__global__ void gather_x_kernel(const float* __restrict__ x, const int* __restrict__ rowtok,
                                unsigned short* __restrict__ Xg) {
    int p = blockIdx.x;
    int tok = rowtok[p];
    const float4* src = (const float4*)(x + (size_t)tok * C_DIM);
    ushort4* dst = (ushort4*)(Xg + (size_t)p * C_DIM);
    int i = threadIdx.x;  // 256 threads x 4 elems = 1024
    float4 v = src[i];
    ushort4 o;
    o.x = f2bf(v.x); o.y = f2bf(v.y); o.z = f2bf(v.z); o.w = f2bf(v.w);
    dst[i] = o;
}

// [E][R][S] fp32 -> [E][S][R] bf16, 64x64 tiles, vectorized both sides.
__global__ __launch_bounds__(256) void transpose_bf16_kernel(
    const float* __restrict__ in, unsigned short* __restrict__ out, int R, int S) {
    __shared__ float tile[64][68];
    const float* ine = in + (size_t)blockIdx.z * R * S;
    unsigned short* oute = out + (size_t)blockIdx.z * R * S;
    int s0 = blockIdx.x * 64, r0 = blockIdx.y * 64;
    int tid = threadIdx.x;
    int rr = tid >> 2, cs = (tid & 3) * 16;
    const float4* src = (const float4*)(ine + (size_t)(r0 + rr) * S + s0 + cs);
#pragma unroll
    for (int q = 0; q < 4; q++) *(float4*)&tile[rr][cs + q * 4] = src[q];
    __syncthreads();
    int ss = tid >> 2, rs = (tid & 3) * 16;
    ushort4 o[4];
#pragma unroll
    for (int q = 0; q < 4; q++) {
        ushort4 v;
        v.x = f2bf(tile[rs + q * 4 + 0][ss]);
        v.y = f2bf(tile[rs + q * 4 + 1][ss]);
        v.z = f2bf(tile[rs + q * 4 + 2][ss]);
        v.w = f2bf(tile[rs + q * 4 + 3][ss]);
        o[q] = v;
    }
    ushort4* dst = (ushort4*)(oute + (size_t)(s0 + ss) * R + r0 + rs);
#pragma unroll
    for (int q = 0; q < 4; q++) dst[q] = o[q];
}

// ---------------------------------------------------------------------------
// R9: 128x128 GEMM, 256 thr = 4 waves (2M x 2N, each 64x64), BK=64, dbuf x2
// = 64KB LDS -> TWO blocks co-resident per CU. Cross-block HW scheduling
// (m114) overlaps one block's LDS/stage/barrier with the other's MFMAs.
// Per K-tile: stage(t+1) (8 gload_lds), 16 ds_read + 32 MFMA free-scheduled,
// then ONE vmcnt(0) + ONE s_barrier (per-block). Swizzle: 128B rows, 16B
// slot s at phys s^(row&7), on gload SOURCE + ds_read addr (rule #21).
// MODE 1: OutH = bf16(relu(acc+bias));  MODE 2: OutC{z} = fp32(acc+(z==0)*bias)
// ---------------------------------------------------------------------------
template <int KDIM, int KLEN, int NDIM, int MODE>
__global__ __launch_bounds__(256, 2) void gemm8_kernel(
    const unsigned short* __restrict__ A, const unsigned short* __restrict__ Bt,
    const float* __restrict__ bias, unsigned short* __restrict__ OutH,
    float* __restrict__ OutC0, float* __restrict__ OutC1,
    const int* __restrict__ meta) {
    extern __shared__ char ldsraw[];  // 65536 bytes

    int nwg = gridDim.x;
    int orig = blockIdx.x;
    int q = nwg >> 3, r8 = nwg & 7;
    int xcd = orig & 7, idx = orig >> 3;
    int wgid = (xcd < r8 ? xcd * (q + 1) : r8 * (q + 1) + (xcd - r8) * q) + idx;
    constexpr int NCT = NDIM / 128;
    int rowBase = (wgid / NCT) * 128;
    int colBase = (wgid % NCT) * 128;
    if (rowBase >= meta[24]) return;
    int e = 0;
#pragma unroll
    for (int i = 1; i < 8; i++)
        if (rowBase >= meta[16 + i]) e = i;
    int koff = blockIdx.z * KLEN;

    int tid = threadIdx.x;
    int wv = tid >> 6, lane = tid & 63;
    int wr = wv >> 1, wc = wv & 1;  // 2M x 2N waves; wave output 64x64

    const unsigned short* Ab = A + (size_t)rowBase * KDIM + koff;
    const unsigned short* Bb = Bt + (size_t)e * NDIM * KDIM + (size_t)colBase * KDIM + koff;

    // Staging decode: chunk j covers rows [j*32, j*32+32); LDS byte (linear)
    // = j*4096 + tid*16; row = (tid>>3)+j*32, src slot = (tid&7)^(row&7).
    int rA = tid >> 3;
    int sSl = ((tid & 7) ^ (rA & 7)) * 8;
    const unsigned short* pA0 = Ab + (size_t)rA * KDIM + sSl;
    const unsigned short* pB0 = Bb + (size_t)rA * KDIM + sSl;

    // Stage one full K-tile (A 128x64 + B 128x64 = 32KB) into buf[tt&1].
#define STAGEALL(tt) { \
        char* base_ = ldsraw + (((tt) & 1) << 15); \
        size_t kadd_ = (size_t)(tt) * 64; \
        _Pragma("unroll") for (int j_ = 0; j_ < 4; j_++) { \
            const unsigned short* sA_ = pA0 + (size_t)j_ * 32 * KDIM + kadd_; \
            const unsigned short* sB_ = pB0 + (size_t)j_ * 32 * KDIM + kadd_; \
            gload_lds16(sA_, base_ + j_ * 4096 + wv * 1024); \
            gload_lds16(sB_, base_ + 16384 + j_ * 4096 + wv * 1024); \
        } }

    // Fragment base addresses (swizzled), constant imm offsets per m/n.
    int physk0 = (lane >> 4) ^ (lane & 7);
    int kdel = ((physk0 ^ 4) - physk0) * 16;  // +-64
    const char* aB0k0 = ldsraw + (wr * 64 + (lane & 15)) * 128 + physk0 * 16;
    const char* aB0k1 = aB0k0 + kdel;
    const char* bB0k0 = ldsraw + 16384 + (wc * 64 + (lane & 15)) * 128 + physk0 * 16;
    const char* bB0k1 = bB0k0 + kdel;

    short8 af[4][2], bf[4][2];
    f32x4 acc[4][4];
#pragma unroll
    for (int m = 0; m < 4; m++)
#pragma unroll
        for (int n = 0; n < 4; n++) acc[m][n] = f32x4{0.f, 0.f, 0.f, 0.f};

#define SB() __builtin_amdgcn_sched_barrier(0)

    constexpr int T = KLEN / 64;

    // Prologue: stage tile 0, drain, sync.
    STAGEALL(0)
    SB(); asm volatile("s_waitcnt vmcnt(0)" ::: "memory"); SB();
    __builtin_amdgcn_s_barrier(); SB();

#pragma unroll 1
    for (int t = 0; t < T; ++t) {
        if (t + 1 < T) STAGEALL(t + 1)
        const char* ak0 = aB0k0 + ((t & 1) << 15);
        const char* ak1 = aB0k1 + ((t & 1) << 15);
        const char* bk0 = bB0k0 + ((t & 1) << 15);
        const char* bk1 = bB0k1 + ((t & 1) << 15);
        // 16 ds_reads + 32 MFMA in one region; compiler lgkmcnt interleaves,
        // cross-block HW scheduling overlaps pipes.
#pragma unroll
        for (int m = 0; m < 4; m++) {
            af[m][0] = *(const short8*)(ak0 + m * 2048);
            af[m][1] = *(const short8*)(ak1 + m * 2048);
        }
#pragma unroll
        for (int n = 0; n < 4; n++) {
            bf[n][0] = *(const short8*)(bk0 + n * 2048);
            bf[n][1] = *(const short8*)(bk1 + n * 2048);
        }
        __builtin_amdgcn_s_setprio(1);
#pragma unroll
        for (int kk = 0; kk < 2; kk++)
#pragma unroll
            for (int m = 0; m < 4; m++)
#pragma unroll
                for (int n = 0; n < 4; n++)
                    acc[m][n] = __builtin_amdgcn_mfma_f32_16x16x32_bf16(
                        af[m][kk], bf[n][kk], acc[m][n], 0, 0, 0);
        __builtin_amdgcn_s_setprio(0);
        // Boundary: my stages for t+1 landed; all waves done reading buf[t&1].
        SB();
        asm volatile("s_waitcnt vmcnt(0)" ::: "memory");
        SB();
        __builtin_amdgcn_s_barrier();
        SB();
    }
#undef STAGEALL

    // Epilogue.
    float bv[4];
#pragma unroll
    for (int n = 0; n < 4; n++)
        bv[n] = bias[(size_t)e * NDIM + colBase + wc * 64 + n * 16 + (lane & 15)];

    if constexpr (MODE == 1) {
        // relu -> bf16, repack via LDS with rr-XOR swizzle, coalesced 16B stores.
        unsigned short* lds16 = (unsigned short*)ldsraw;  // 128x128 bf16 = 32KB
#pragma unroll
        for (int m = 0; m < 4; m++) {
#pragma unroll
            for (int n = 0; n < 4; n++) {
#pragma unroll
                for (int j = 0; j < 4; j++) {
                    float v = fmaxf(acc[m][n][j] + bv[n], 0.f);
                    int rr = wr * 64 + m * 16 + (lane >> 4) * 4 + j;
                    int cc = wc * 64 + n * 16 + (lane & 15);
                    lds16[rr * 128 + (cc ^ ((rr & 7) << 4))] = f2bf(v);
                }
            }
        }
        __syncthreads();
        int row = tid >> 1, half = tid & 1;
        int xr = (row & 7) << 4;
#pragma unroll
        for (int i = 0; i < 8; i++) {
            int cs = half * 64 + i * 8;
            short8 val = *(const short8*)(lds16 + row * 128 + (cs ^ xr));
            *(short8*)(OutH + (size_t)(rowBase + row) * NDIM + colBase + cs) = val;
        }
    } else {
        float* Of = (blockIdx.z == 0) ? OutC0 : OutC1;
        if (blockIdx.z != 0) {
#pragma unroll
            for (int n = 0; n < 4; n++) bv[n] = 0.f;
        }
#pragma unroll
        for (int m = 0; m < 4; m++) {
#pragma unroll
            for (int n = 0; n < 4; n++) {
#pragma unroll
                for (int j = 0; j < 4; j++) {
                    int rr = wr * 64 + m * 16 + (lane >> 4) * 4 + j;
                    int cc = wc * 64 + n * 16 + (lane & 15);
                    Of[(size_t)(rowBase + rr) * NDIM + colBase + cc] = acc[m][n][j] + bv[n];
                }
            }
        }
    }
}

// out[t] = w0*(c0[p0]+c1[p0]) + w1*(c0[p1]+c1[p1])  (fixed order, deterministic)
__global__ void combine_kernel(const float* __restrict__ c0, const float* __restrict__ c1,
                               const int2* __restrict__ tok_pos, const float2* __restrict__ tok_w,
                               float* __restrict__ out) {
    int t = blockIdx.x;
    int2 p = tok_pos[t];
    float2 w = tok_w[t];
    int i = threadIdx.x;
    float4 a0 = ((const float4*)(c0 + (size_t)p.x * C_DIM))[i];
    float4 a1 = ((const float4*)(c1 + (size_t)p.x * C_DIM))[i];
    float4 b0 = ((const float4*)(c0 + (size_t)p.y * C_DIM))[i];
    float4 b1 = ((const float4*)(c1 + (size_t)p.y * C_DIM))[i];
    float4 r;
    r.x = w.x * (a0.x + a1.x) + w.y * (b0.x + b1.x);
    r.y = w.x * (a0.y + a1.y) + w.y * (b0.y + b1.y);
    r.z = w.x * (a0.z + a1.z) + w.y * (b0.z + b1.z);
    r.w = w.x * (a0.w + a1.w) + w.y * (b0.w + b1.w);
    ((float4*)(out + (size_t)t * C_DIM))[i] = r;
}

extern "C" void kernel_launch(void* const* d_in, const int* in_sizes, int n_in,
                              void* d_out, int out_size, void* d_ws, size_t ws_size,
                              hipStream_t stream) {
    (void)in_sizes; (void)n_in; (void)out_size; (void)ws_size;
    const float* x       = (const float*)d_in[0];
    const float* noise   = (const float*)d_in[1];
    const float* w_gate  = (const float*)d_in[2];
    const float* b_gate  = (const float*)d_in[3];
    const float* w_noise = (const float*)d_in[4];
    const float* b_noise = (const float*)d_in[5];
    const float* w1      = (const float*)d_in[6];
    const float* b1      = (const float*)d_in[7];
    const float* w2      = (const float*)d_in[8];
    const float* b2      = (const float*)d_in[9];
    float* out = (float*)d_out;

    char* w = (char*)d_ws;
    size_t off = 0;
    int* meta = (int*)(w + off); off += 256;
    float* wT = (float*)(w + off); off += 16 * C_DIM * 4;
    int2* tok_e = (int2*)(w + off); off += (size_t)NTOK * 8;
    float2* tok_w = (float2*)(w + off); off += (size_t)NTOK * 8;
    int2* tok_pos = (int2*)(w + off); off += (size_t)NTOK * 8;
    int* rowtok = (int*)(w + off); off += (size_t)MAXROWS * 4;
    unsigned short* H = (unsigned short*)(w + off); off += (size_t)MAXROWS * DFF_DIM * 2;
    unsigned short* w2b = (unsigned short*)(w + off); off += (size_t)E_NUM * C_DIM * DFF_DIM * 2;
    float* c0 = (float*)(w + off); off += (size_t)MAXROWS * C_DIM * 4;
    unsigned short* Xg = (unsigned short*)(w + off); off += (size_t)MAXROWS * C_DIM * 2;
    unsigned short* w1b = (unsigned short*)(w + off); off += (size_t)E_NUM * DFF_DIM * C_DIM * 2;
    // c1 aliases [Xg, Xg + 75.5MB): Xg/w1b are dead once gemm1 has run, and
    // both are fully rewritten by gather/transpose on every call (replay-safe).
    float* c1 = (float*)Xg;

    init_kernel<<<(MAXROWS + 255) / 256, 256, 0, stream>>>(meta, rowtok);
    wrouter_T_kernel<<<64, 256, 0, stream>>>(w_gate, w_noise, wT);
    router_kernel<<<NTOK / 32, 256, 0, stream>>>(x, noise, wT, b_gate, b_noise,
                                                 meta, tok_e, tok_w);
    offsets_kernel<<<1, 64, 0, stream>>>(meta);
    assign_kernel<<<NTOK / 256, 256, 0, stream>>>(meta, tok_e, tok_pos, rowtok);
    gather_x_kernel<<<MAXROWS, 256, 0, stream>>>(x, rowtok, Xg);
    transpose_bf16_kernel<<<dim3(DFF_DIM / 64, C_DIM / 64, E_NUM), 256, 0, stream>>>(w1, w1b, C_DIM, DFF_DIM);
    transpose_bf16_kernel<<<dim3(C_DIM / 64, DFF_DIM / 64, E_NUM), 256, 0, stream>>>(w2, w2b, DFF_DIM, C_DIM);

    hipFuncSetAttribute((const void*)gemm8_kernel<C_DIM, C_DIM, DFF_DIM, 1>,
                        hipFuncAttributeMaxDynamicSharedMemorySize, 65536);
    gemm8_kernel<C_DIM, C_DIM, DFF_DIM, 1>
        <<<dim3((MAXROWS / 128) * (DFF_DIM / 128), 1, 1), 256, 65536, stream>>>(
            Xg, w1b, b1, H, nullptr, nullptr, meta);

    hipFuncSetAttribute((const void*)gemm8_kernel<DFF_DIM, DFF_DIM / 2, C_DIM, 2>,
                        hipFuncAttributeMaxDynamicSharedMemorySize, 65536);
    gemm8_kernel<DFF_DIM, DFF_DIM / 2, C_DIM, 2>
        <<<dim3((MAXROWS / 128) * (C_DIM / 128), 1, 2), 256, 65536, stream>>>(
            H, w2b, b2, nullptr, c0, c1, meta);

    combine_kernel<<<NTOK, 256, 0, stream>>>(c0, c1, tok_pos, tok_w, out);
}

// Round 10
// 741.453 us; speedup vs baseline: 1.0478x; 1.0478x over previous
//
#include <hip/hip_runtime.h>
#include <hip/hip_bf16.h>
#include <cmath>

#define DEVFN __device__ __forceinline__

typedef __attribute__((ext_vector_type(8))) short short8;
typedef __attribute__((ext_vector_type(4))) float f32x4;

constexpr int C_DIM   = 1024;
constexpr int E_NUM   = 8;
constexpr int DFF_DIM = 4096;
constexpr int NTOK    = 8192;       // B*T
constexpr int PAD     = 256;        // expert segment alignment
constexpr int MAXROWS = NTOK * 2 + E_NUM * PAD;  // 18432

DEVFN unsigned short f2bf(float f) {
    __hip_bfloat16 h = __float2bfloat16(f);
    return __builtin_bit_cast(unsigned short, h);
}
DEVFN float bf2f(unsigned short u) {
    return __bfloat162float(__builtin_bit_cast(__hip_bfloat16, u));
}
DEVFN void gload_lds16(const void* g, void* lds) {
    __builtin_amdgcn_global_load_lds(
        (const __attribute__((address_space(1))) unsigned int*)g,
        (__attribute__((address_space(3))) unsigned int*)lds, 16, 0, 0);
}

// meta layout (ints): [0..7] counts, [8..15] cursor, [16..24] offs (offs[8]=padTotal)

// init: zero meta + rowtok, and build wT[o][c] (o<8 gate, o>=8 noise).
__global__ void init_kernel(int* meta, int* rowtok,
                            const float* __restrict__ wg, const float* __restrict__ wn,
                            float* __restrict__ wT) {
    int gid = blockIdx.x * 256 + threadIdx.x;
    if (gid < 64) meta[gid] = 0;
    if (gid < MAXROWS) rowtok[gid] = 0;
    if (gid < 16 * C_DIM) {
        int o = gid >> 10, c = gid & 1023;
        wT[gid] = (o < 8) ? wg[c * 8 + o] : wn[c * 8 + (o - 8)];
    }
}

// Router: 32 tokens/block, 8 threads/token. Coalesced x float4 loads,
// broadcast wT loads, fp64 accumulation (exact products, fp64 adds).
__global__ __launch_bounds__(256) void router_kernel(
    const float* __restrict__ x, const float* __restrict__ noise,
    const float* __restrict__ wT, const float* __restrict__ bg,
    const float* __restrict__ bn, int* meta, int2* tok_e, float2* tok_w) {
    int tid = threadIdx.x;
    int tt = tid >> 3, sub = tid & 7;
    int tok = blockIdx.x * 32 + tt;
    const float* xr = x + (size_t)tok * C_DIM;

    double acc[16];
#pragma unroll
    for (int o = 0; o < 16; o++) acc[o] = 0.0;

#pragma unroll 4
    for (int i = 0; i < 32; i++) {
        int c = i * 32 + sub * 4;
        float4 xv = *(const float4*)(xr + c);
#pragma unroll
        for (int o = 0; o < 16; o++) {
            float4 wv = *(const float4*)(wT + o * C_DIM + c);
            acc[o] += (double)xv.x * (double)wv.x;
            acc[o] += (double)xv.y * (double)wv.y;
            acc[o] += (double)xv.z * (double)wv.z;
            acc[o] += (double)xv.w * (double)wv.w;
        }
    }
#pragma unroll
    for (int s = 1; s <= 4; s <<= 1) {
#pragma unroll
        for (int o = 0; o < 16; o++) acc[o] += __shfl_xor(acc[o], s, 64);
    }
    if (sub == 0) {
        double logit[8];
#pragma unroll
        for (int e = 0; e < 8; e++) {
            double cl = acc[e] + (double)bg[e];
            double nl = acc[8 + e] + (double)bn[e];
            double sp = (nl > 30.0) ? nl : log1p(exp(nl));
            logit[e] = cl + (double)noise[(size_t)tok * 8 + e] * sp;
        }
        int i1 = -1, i2 = -1;
        double v1 = -1e300, v2 = -1e300;
#pragma unroll
        for (int e = 0; e < 8; e++) {
            double v = logit[e];
            if (v > v1) { v2 = v1; i2 = i1; v1 = v; i1 = e; }
            else if (v > v2) { v2 = v; i2 = e; }
        }
        double d = exp(v2 - v1);
        tok_e[tok] = make_int2(i1, i2);
        tok_w[tok] = make_float2((float)(1.0 / (1.0 + d)), (float)(d / (1.0 + d)));
        atomicAdd(&meta[i1], 1);
        atomicAdd(&meta[i2], 1);
    }
}

__global__ void offsets_kernel(int* meta) {
    if (threadIdx.x == 0 && blockIdx.x == 0) {
        int off = 0;
        for (int e = 0; e < 8; e++) {
            meta[16 + e] = off;
            off += (meta[e] + PAD - 1) / PAD * PAD;
            meta[8 + e] = 0;  // cursor
        }
        meta[24] = off;  // padTotal
    }
}

// Wave-aggregated slot assignment (atomic order doesn't affect any FP result).
__global__ void assign_kernel(int* meta, const int2* tok_e,
                              int2* tok_pos, int* rowtok) {
    int t = blockIdx.x * 256 + threadIdx.x;
    int lane = threadIdx.x & 63;
    int2 e = tok_e[t];
    int sel[2] = {e.x, e.y};
    int pos[2];
#pragma unroll
    for (int s = 0; s < 2; s++) {
        int p = 0;
#pragma unroll
        for (int ex = 0; ex < 8; ex++) {
            unsigned long long m = __ballot(sel[s] == ex);
            if (m) {
                int leader = __ffsll((unsigned long long)m) - 1;
                int base = 0;
                if (lane == leader) base = atomicAdd(&meta[8 + ex], (int)__popcll(m));
                base = __shfl(base, leader, 64);
                if (sel[s] == ex)
                    p = meta[16 + ex] + base + (int)__popcll(m & ((1ull << lane) - 1ull));
            }
        }
        pos[s] = p;
        rowtok[p] = t;
    }
    tok_pos[t] = make_int2(pos[0], pos[1]);
}

// Transpose body: [R][S] fp32 tile (r0,s0) -> [S][R] bf16, 64x64, vectorized.
DEVFN void transpose_body(const float* __restrict__ ine, unsigned short* __restrict__ oute,
                          int R, int S, int r0, int s0, float (*tile)[68]) {
    int tid = threadIdx.x;
    int rr = tid >> 2, cs = (tid & 3) * 16;
    const float4* src = (const float4*)(ine + (size_t)(r0 + rr) * S + s0 + cs);
#pragma unroll
    for (int q = 0; q < 4; q++) *(float4*)&tile[rr][cs + q * 4] = src[q];
    __syncthreads();
    int ss = tid >> 2, rs = (tid & 3) * 16;
    ushort4 o[4];
#pragma unroll
    for (int q = 0; q < 4; q++) {
        ushort4 v;
        v.x = f2bf(tile[rs + q * 4 + 0][ss]);
        v.y = f2bf(tile[rs + q * 4 + 1][ss]);
        v.z = f2bf(tile[rs + q * 4 + 2][ss]);
        v.w = f2bf(tile[rs + q * 4 + 3][ss]);
        o[q] = v;
    }
    ushort4* dst = (ushort4*)(oute + (size_t)(s0 + ss) * R + r0 + rs);
#pragma unroll
    for (int q = 0; q < 4; q++) dst[q] = o[q];
}

// prep: fused {transpose w1, transpose w2, gather x} by block range.
constexpr int NB_T1 = (DFF_DIM / 64) * (C_DIM / 64) * E_NUM;  // 8192
constexpr int NB_T2 = (C_DIM / 64) * (DFF_DIM / 64) * E_NUM;  // 8192
__global__ __launch_bounds__(256) void prep_kernel(
    const float* __restrict__ w1, unsigned short* __restrict__ w1b,
    const float* __restrict__ w2, unsigned short* __restrict__ w2b,
    const float* __restrict__ x, const int* __restrict__ rowtok,
    unsigned short* __restrict__ Xg) {
    __shared__ float tile[64][68];
    int b = blockIdx.x;
    if (b < NB_T1) {
        int bx = b & 63, by = (b >> 6) & 15, bz = b >> 10;
        transpose_body(w1 + (size_t)bz * C_DIM * DFF_DIM,
                       w1b + (size_t)bz * C_DIM * DFF_DIM,
                       C_DIM, DFF_DIM, by * 64, bx * 64, tile);
        return;
    }
    b -= NB_T1;
    if (b < NB_T2) {
        int bx = b & 15, by = (b >> 4) & 63, bz = b >> 10;
        transpose_body(w2 + (size_t)bz * C_DIM * DFF_DIM,
                       w2b + (size_t)bz * C_DIM * DFF_DIM,
                       DFF_DIM, C_DIM, by * 64, bx * 64, tile);
        return;
    }
    b -= NB_T2;
    // gather row b
    int tok = rowtok[b];
    const float4* src = (const float4*)(x + (size_t)tok * C_DIM);
    ushort4* dst = (ushort4*)(Xg + (size_t)b * C_DIM);
    int i = threadIdx.x;
    float4 v = src[i];
    ushort4 o;
    o.x = f2bf(v.x); o.y = f2bf(v.y); o.z = f2bf(v.z); o.w = f2bf(v.w);
    dst[i] = o;
}

// ---------------------------------------------------------------------------
// 256x256 GEMM (measured-best R8 structure), 512 thr = 8 waves (2M x 4N),
// BK=64, dbuf x2 (2 x 64KB LDS). Per K-tile: stage(t+1) (8 gload_lds), then
// 24 ds_read + 64 MFMA free-scheduled, ONE vmcnt(0) + ONE s_barrier.
// Swizzle: 128B rows, 16B slot s at phys s^(row&7) on gload SOURCE + read.
// Unified epilogue -> bf16 via LDS repack, coalesced 16B stores.
// MODE 1: relu(acc+bias) -> OutH.  MODE 2: acc + (z==0)*bias -> OutC{z}.
// ---------------------------------------------------------------------------
template <int KDIM, int KLEN, int NDIM, int MODE>
__global__ __launch_bounds__(512, 2) void gemm8_kernel(
    const unsigned short* __restrict__ A, const unsigned short* __restrict__ Bt,
    const float* __restrict__ bias, unsigned short* __restrict__ OutH,
    unsigned short* __restrict__ OutC0, unsigned short* __restrict__ OutC1,
    const int* __restrict__ meta) {
    extern __shared__ char ldsraw[];  // 131072 bytes

    int nwg = gridDim.x;
    int orig = blockIdx.x;
    int q = nwg >> 3, r8 = nwg & 7;
    int xcd = orig & 7, idx = orig >> 3;
    int wgid = (xcd < r8 ? xcd * (q + 1) : r8 * (q + 1) + (xcd - r8) * q) + idx;
    constexpr int NCT = NDIM / 256;
    int rowBase = (wgid / NCT) * 256;
    int colBase = (wgid % NCT) * 256;
    if (rowBase >= meta[24]) return;
    int e = 0;
#pragma unroll
    for (int i = 1; i < 8; i++)
        if (rowBase >= meta[16 + i]) e = i;
    int koff = blockIdx.z * KLEN;

    int tid = threadIdx.x;
    int wv = tid >> 6, lane = tid & 63;
    int wr = wv >> 2, wcol = wv & 3;  // 2M x 4N waves; wave output 128x64

    const unsigned short* Ab = A + (size_t)rowBase * KDIM + koff;
    const unsigned short* Bb = Bt + (size_t)e * NDIM * KDIM + (size_t)colBase * KDIM + koff;

    int rA = tid >> 3;
    int sSl = ((tid & 7) ^ (rA & 7)) * 8;
    const unsigned short* pA0 = Ab + (size_t)rA * KDIM + sSl;
    const unsigned short* pB0 = Bb + (size_t)rA * KDIM + sSl;

#define STAGEALL(tt) { \
        char* base_ = ldsraw + (((tt) & 1) << 16); \
        size_t kadd_ = (size_t)(tt) * 64; \
        _Pragma("unroll") for (int h_ = 0; h_ < 2; h_++) { \
            char* dA_ = base_ + h_ * 16384 + wv * 1024; \
            const unsigned short* sA_ = pA0 + (size_t)h_ * (128 * KDIM) + kadd_; \
            gload_lds16(sA_, dA_); \
            gload_lds16(sA_ + (size_t)64 * KDIM, dA_ + 8192); \
            char* dB_ = base_ + 32768 + h_ * 16384 + wv * 1024; \
            const unsigned short* sB_ = pB0 + (size_t)h_ * (128 * KDIM) + kadd_; \
            gload_lds16(sB_, dB_); \
            gload_lds16(sB_ + (size_t)64 * KDIM, dB_ + 8192); \
        } }

    int physk0 = (lane >> 4) ^ (lane & 7);
    int kdel = ((physk0 ^ 4) - physk0) * 16;  // +-64
    const char* aB0k0 = ldsraw + wr * 16384 + (lane & 15) * 128 + physk0 * 16;
    const char* aB0k1 = aB0k0 + kdel;
    const char* bB0k0 = ldsraw + 32768 + (wcol >> 1) * 16384 +
                        ((wcol & 1) * 64 + (lane & 15)) * 128 + physk0 * 16;
    const char* bB0k1 = bB0k0 + kdel;

    short8 afA[4][2], afB[4][2], bfA[2][2], bfB[2][2];
    f32x4 acc[8][4];
#pragma unroll
    for (int m = 0; m < 8; m++)
#pragma unroll
        for (int n = 0; n < 4; n++) acc[m][n] = f32x4{0.f, 0.f, 0.f, 0.f};

#define LDA(DST, K0, K1, MOFF) \
    _Pragma("unroll") for (int mm = 0; mm < 4; mm++) { \
        DST[mm][0] = *(const short8*)((K0) + ((MOFF) + mm) * 2048); \
        DST[mm][1] = *(const short8*)((K1) + ((MOFF) + mm) * 2048); }
#define LDB(DST, K0, K1, NOFF) \
    _Pragma("unroll") for (int nn = 0; nn < 2; nn++) { \
        DST[nn][0] = *(const short8*)((K0) + ((NOFF) + nn) * 2048); \
        DST[nn][1] = *(const short8*)((K1) + ((NOFF) + nn) * 2048); }
#define QUAD(AF, BF, MB, NB) \
    __builtin_amdgcn_s_setprio(1); \
    _Pragma("unroll") for (int kk = 0; kk < 2; kk++) \
    _Pragma("unroll") for (int mm = 0; mm < 4; mm++) \
    _Pragma("unroll") for (int nn = 0; nn < 2; nn++) \
        acc[(MB) + mm][(NB) + nn] = __builtin_amdgcn_mfma_f32_16x16x32_bf16( \
            AF[mm][kk], BF[nn][kk], acc[(MB) + mm][(NB) + nn], 0, 0, 0); \
    __builtin_amdgcn_s_setprio(0);
#define SB() __builtin_amdgcn_sched_barrier(0)

    constexpr int T = KLEN / 64;

    STAGEALL(0)
    SB(); asm volatile("s_waitcnt vmcnt(0)" ::: "memory"); SB();
    __builtin_amdgcn_s_barrier(); SB();

#pragma unroll 1
    for (int t = 0; t < T; ++t) {
        if (t + 1 < T) STAGEALL(t + 1)
        const char* ak0 = aB0k0 + ((t & 1) << 16);
        const char* ak1 = aB0k1 + ((t & 1) << 16);
        const char* bk0 = bB0k0 + ((t & 1) << 16);
        const char* bk1 = bB0k1 + ((t & 1) << 16);
        LDA(afA, ak0, ak1, 0)
        LDB(bfA, bk0, bk1, 0)
        LDB(bfB, bk0, bk1, 2)
        QUAD(afA, bfA, 0, 0)
        LDA(afB, ak0, ak1, 4)
        QUAD(afA, bfB, 0, 2)
        QUAD(afB, bfA, 4, 0)
        QUAD(afB, bfB, 4, 2)
        SB();
        asm volatile("s_waitcnt vmcnt(0)" ::: "memory");
        SB();
        __builtin_amdgcn_s_barrier();
        SB();
    }
#undef STAGEALL
#undef LDA
#undef LDB
#undef QUAD

    // Unified epilogue: bf16 via LDS repack with rr-XOR swizzle.
    float bv[4];
    bool addBias = (MODE == 1) || (blockIdx.z == 0);
#pragma unroll
    for (int n = 0; n < 4; n++)
        bv[n] = addBias ? bias[(size_t)e * NDIM + colBase + wcol * 64 + n * 16 + (lane & 15)]
                        : 0.f;
    unsigned short* OutP = (MODE == 1) ? OutH : (blockIdx.z == 0 ? OutC0 : OutC1);

    unsigned short* lds16 = (unsigned short*)ldsraw;
#pragma unroll
    for (int m = 0; m < 8; m++) {
#pragma unroll
        for (int n = 0; n < 4; n++) {
#pragma unroll
            for (int j = 0; j < 4; j++) {
                float v = acc[m][n][j] + bv[n];
                if (MODE == 1) v = fmaxf(v, 0.f);
                int rr = wr * 128 + m * 16 + (lane >> 4) * 4 + j;
                int cc = wcol * 64 + n * 16 + (lane & 15);
                lds16[rr * 256 + (cc ^ ((rr & 7) << 4))] = f2bf(v);
            }
        }
    }
    __syncthreads();
    {
        int row = tid >> 1, half = tid & 1;
        int xr = (row & 7) << 4;
#pragma unroll
        for (int i = 0; i < 16; i++) {
            int cs = half * 128 + i * 8;
            short8 val = *(const short8*)(lds16 + row * 256 + (cs ^ xr));
            *(short8*)(OutP + (size_t)(rowBase + row) * NDIM + colBase + cs) = val;
        }
    }
}

// out[t] = w0*(c0[p0]+c1[p0]) + w1*(c0[p1]+c1[p1])  (fixed order, deterministic)
__global__ void combine_kernel(const unsigned short* __restrict__ c0,
                               const unsigned short* __restrict__ c1,
                               const int2* __restrict__ tok_pos, const float2* __restrict__ tok_w,
                               float* __restrict__ out) {
    int t = blockIdx.x;
    int2 p = tok_pos[t];
    float2 w = tok_w[t];
    int i = threadIdx.x;  // 256 x 4 elems
    ushort4 a0 = ((const ushort4*)(c0 + (size_t)p.x * C_DIM))[i];
    ushort4 a1 = ((const ushort4*)(c1 + (size_t)p.x * C_DIM))[i];
    ushort4 b0 = ((const ushort4*)(c0 + (size_t)p.y * C_DIM))[i];
    ushort4 b1 = ((const ushort4*)(c1 + (size_t)p.y * C_DIM))[i];
    float4 r;
    r.x = w.x * (bf2f(a0.x) + bf2f(a1.x)) + w.y * (bf2f(b0.x) + bf2f(b1.x));
    r.y = w.x * (bf2f(a0.y) + bf2f(a1.y)) + w.y * (bf2f(b0.y) + bf2f(b1.y));
    r.z = w.x * (bf2f(a0.z) + bf2f(a1.z)) + w.y * (bf2f(b0.z) + bf2f(b1.z));
    r.w = w.x * (bf2f(a0.w) + bf2f(a1.w)) + w.y * (bf2f(b0.w) + bf2f(b1.w));
    ((float4*)(out + (size_t)t * C_DIM))[i] = r;
}

extern "C" void kernel_launch(void* const* d_in, const int* in_sizes, int n_in,
                              void* d_out, int out_size, void* d_ws, size_t ws_size,
                              hipStream_t stream) {
    (void)in_sizes; (void)n_in; (void)out_size; (void)ws_size;
    const float* x       = (const float*)d_in[0];
    const float* noise   = (const float*)d_in[1];
    const float* w_gate  = (const float*)d_in[2];
    const float* b_gate  = (const float*)d_in[3];
    const float* w_noise = (const float*)d_in[4];
    const float* b_noise = (const float*)d_in[5];
    const float* w1      = (const float*)d_in[6];
    const float* b1      = (const float*)d_in[7];
    const float* w2      = (const float*)d_in[8];
    const float* b2      = (const float*)d_in[9];
    float* out = (float*)d_out;

    char* w = (char*)d_ws;
    size_t off = 0;
    int* meta = (int*)(w + off); off += 256;
    float* wT = (float*)(w + off); off += 16 * C_DIM * 4;
    int2* tok_e = (int2*)(w + off); off += (size_t)NTOK * 8;
    float2* tok_w = (float2*)(w + off); off += (size_t)NTOK * 8;
    int2* tok_pos = (int2*)(w + off); off += (size_t)NTOK * 8;
    int* rowtok = (int*)(w + off); off += (size_t)MAXROWS * 4;
    unsigned short* H = (unsigned short*)(w + off); off += (size_t)MAXROWS * DFF_DIM * 2;
    unsigned short* w2b = (unsigned short*)(w + off); off += (size_t)E_NUM * C_DIM * DFF_DIM * 2;
    unsigned short* c0 = (unsigned short*)(w + off); off += (size_t)MAXROWS * C_DIM * 2;
    unsigned short* Xg = (unsigned short*)(w + off); off += (size_t)MAXROWS * C_DIM * 2;
    unsigned short* w1b = (unsigned short*)(w + off); off += (size_t)E_NUM * DFF_DIM * C_DIM * 2;
    // c1 aliases Xg (same size): Xg is dead once gemm1 has run, and is fully
    // rewritten by prep on every call (replay-safe).
    unsigned short* c1 = Xg;

    init_kernel<<<(MAXROWS + 255) / 256, 256, 0, stream>>>(meta, rowtok, w_gate, w_noise, wT);
    router_kernel<<<NTOK / 32, 256, 0, stream>>>(x, noise, wT, b_gate, b_noise,
                                                 meta, tok_e, tok_w);
    offsets_kernel<<<1, 64, 0, stream>>>(meta);
    assign_kernel<<<NTOK / 256, 256, 0, stream>>>(meta, tok_e, tok_pos, rowtok);
    prep_kernel<<<NB_T1 + NB_T2 + MAXROWS, 256, 0, stream>>>(w1, w1b, w2, w2b, x, rowtok, Xg);

    hipFuncSetAttribute((const void*)gemm8_kernel<C_DIM, C_DIM, DFF_DIM, 1>,
                        hipFuncAttributeMaxDynamicSharedMemorySize, 131072);
    gemm8_kernel<C_DIM, C_DIM, DFF_DIM, 1>
        <<<dim3((MAXROWS / 256) * (DFF_DIM / 256), 1, 1), 512, 131072, stream>>>(
            Xg, w1b, b1, H, nullptr, nullptr, meta);

    hipFuncSetAttribute((const void*)gemm8_kernel<DFF_DIM, DFF_DIM / 2, C_DIM, 2>,
                        hipFuncAttributeMaxDynamicSharedMemorySize, 131072);
    gemm8_kernel<DFF_DIM, DFF_DIM / 2, C_DIM, 2>
        <<<dim3((MAXROWS / 256) * (C_DIM / 256), 1, 2), 512, 131072, stream>>>(
            H, w2b, b2, nullptr, c0, c1, meta);

    combine_kernel<<<NTOK, 256, 0, stream>>>(c0, c1, tok_pos, tok_w, out);
}

// Round 11
// 633.758 us; speedup vs baseline: 1.2259x; 1.1699x over previous
//
#include <hip/hip_runtime.h>
#include <hip/hip_bf16.h>
#include <cmath>

#define DEVFN __device__ __forceinline__

typedef __attribute__((ext_vector_type(8))) short short8;
typedef __attribute__((ext_vector_type(4))) float f32x4;

constexpr int C_DIM   = 1024;
constexpr int E_NUM   = 8;
constexpr int DFF_DIM = 4096;
constexpr int NTOK    = 8192;       // B*T
constexpr int PAD     = 256;        // expert segment alignment
constexpr int MAXROWS = NTOK * 2 + E_NUM * PAD;  // 18432

DEVFN unsigned short f2bf(float f) {
    __hip_bfloat16 h = __float2bfloat16(f);
    return __builtin_bit_cast(unsigned short, h);
}
DEVFN float bf2f(unsigned short u) {
    return __bfloat162float(__builtin_bit_cast(__hip_bfloat16, u));
}
DEVFN void gload_lds16(const void* g, void* lds) {
    __builtin_amdgcn_global_load_lds(
        (const __attribute__((address_space(1))) unsigned int*)g,
        (__attribute__((address_space(3))) unsigned int*)lds, 16, 0, 0);
}

// meta layout (ints): [0..7] counts, [8..15] cursor, [16..24] offs (offs[8]=padTotal)

// init: zero meta + rowtok, and build wT[o][c] (o<8 gate, o>=8 noise).
__global__ void init_kernel(int* meta, int* rowtok,
                            const float* __restrict__ wg, const float* __restrict__ wn,
                            float* __restrict__ wT) {
    int gid = blockIdx.x * 256 + threadIdx.x;
    if (gid < 64) meta[gid] = 0;
    if (gid < MAXROWS) rowtok[gid] = 0;
    if (gid < 16 * C_DIM) {
        int o = gid >> 10, c = gid & 1023;
        wT[gid] = (o < 8) ? wg[c * 8 + o] : wn[c * 8 + (o - 8)];
    }
}

// Router v3: 32 tokens/block, 8 threads/token. wT (64KB) staged in LDS once
// per block -> weight reads are conflict-free ds_read_b128 broadcasts; only
// global load in the loop is the coalesced x float4. fp64 accumulation
// (exact products, fp64 adds) - bit-identical math to R6-R10 router.
__global__ __launch_bounds__(256) void router_kernel(
    const float* __restrict__ x, const float* __restrict__ noise,
    const float* __restrict__ wT, const float* __restrict__ bg,
    const float* __restrict__ bn, int* meta, int2* tok_e, float2* tok_w) {
    extern __shared__ float swT[];  // 16*1024 floats = 64KB
    int tid = threadIdx.x;
#pragma unroll
    for (int j = 0; j < 16; j++) {
        int idx = (j * 256 + tid) * 4;
        *(float4*)&swT[idx] = *(const float4*)&wT[idx];
    }
    __syncthreads();

    int tt = tid >> 3, sub = tid & 7;
    int tok = blockIdx.x * 32 + tt;
    const float* xr = x + (size_t)tok * C_DIM;

    double acc[16];
#pragma unroll
    for (int o = 0; o < 16; o++) acc[o] = 0.0;

#pragma unroll 4
    for (int i = 0; i < 32; i++) {
        int c = i * 32 + sub * 4;
        float4 xv = *(const float4*)(xr + c);
#pragma unroll
        for (int o = 0; o < 16; o++) {
            float4 wv = *(const float4*)(&swT[o * C_DIM + c]);
            acc[o] += (double)xv.x * (double)wv.x;
            acc[o] += (double)xv.y * (double)wv.y;
            acc[o] += (double)xv.z * (double)wv.z;
            acc[o] += (double)xv.w * (double)wv.w;
        }
    }
#pragma unroll
    for (int s = 1; s <= 4; s <<= 1) {
#pragma unroll
        for (int o = 0; o < 16; o++) acc[o] += __shfl_xor(acc[o], s, 64);
    }
    if (sub == 0) {
        double logit[8];
#pragma unroll
        for (int e = 0; e < 8; e++) {
            double cl = acc[e] + (double)bg[e];
            double nl = acc[8 + e] + (double)bn[e];
            double sp = (nl > 30.0) ? nl : log1p(exp(nl));
            logit[e] = cl + (double)noise[(size_t)tok * 8 + e] * sp;
        }
        int i1 = -1, i2 = -1;
        double v1 = -1e300, v2 = -1e300;
#pragma unroll
        for (int e = 0; e < 8; e++) {
            double v = logit[e];
            if (v > v1) { v2 = v1; i2 = i1; v1 = v; i1 = e; }
            else if (v > v2) { v2 = v; i2 = e; }
        }
        double d = exp(v2 - v1);
        tok_e[tok] = make_int2(i1, i2);
        tok_w[tok] = make_float2((float)(1.0 / (1.0 + d)), (float)(d / (1.0 + d)));
        atomicAdd(&meta[i1], 1);
        atomicAdd(&meta[i2], 1);
    }
}

__global__ void offsets_kernel(int* meta) {
    if (threadIdx.x == 0 && blockIdx.x == 0) {
        int off = 0;
        for (int e = 0; e < 8; e++) {
            meta[16 + e] = off;
            off += (meta[e] + PAD - 1) / PAD * PAD;
            meta[8 + e] = 0;  // cursor
        }
        meta[24] = off;  // padTotal
    }
}

// Wave-aggregated slot assignment (atomic order doesn't affect any FP result).
__global__ void assign_kernel(int* meta, const int2* tok_e,
                              int2* tok_pos, int* rowtok) {
    int t = blockIdx.x * 256 + threadIdx.x;
    int lane = threadIdx.x & 63;
    int2 e = tok_e[t];
    int sel[2] = {e.x, e.y};
    int pos[2];
#pragma unroll
    for (int s = 0; s < 2; s++) {
        int p = 0;
#pragma unroll
        for (int ex = 0; ex < 8; ex++) {
            unsigned long long m = __ballot(sel[s] == ex);
            if (m) {
                int leader = __ffsll((unsigned long long)m) - 1;
                int base = 0;
                if (lane == leader) base = atomicAdd(&meta[8 + ex], (int)__popcll(m));
                base = __shfl(base, leader, 64);
                if (sel[s] == ex)
                    p = meta[16 + ex] + base + (int)__popcll(m & ((1ull << lane) - 1ull));
            }
        }
        pos[s] = p;
        rowtok[p] = t;
    }
    tok_pos[t] = make_int2(pos[0], pos[1]);
}

// Transpose body: [R][S] fp32 tile (r0,s0) -> [S][R] bf16, 64x64, vectorized.
DEVFN void transpose_body(const float* __restrict__ ine, unsigned short* __restrict__ oute,
                          int R, int S, int r0, int s0, float (*tile)[68]) {
    int tid = threadIdx.x;
    int rr = tid >> 2, cs = (tid & 3) * 16;
    const float4* src = (const float4*)(ine + (size_t)(r0 + rr) * S + s0 + cs);
#pragma unroll
    for (int q = 0; q < 4; q++) *(float4*)&tile[rr][cs + q * 4] = src[q];
    __syncthreads();
    int ss = tid >> 2, rs = (tid & 3) * 16;
    ushort4 o[4];
#pragma unroll
    for (int q = 0; q < 4; q++) {
        ushort4 v;
        v.x = f2bf(tile[rs + q * 4 + 0][ss]);
        v.y = f2bf(tile[rs + q * 4 + 1][ss]);
        v.z = f2bf(tile[rs + q * 4 + 2][ss]);
        v.w = f2bf(tile[rs + q * 4 + 3][ss]);
        o[q] = v;
    }
    ushort4* dst = (ushort4*)(oute + (size_t)(s0 + ss) * R + r0 + rs);
#pragma unroll
    for (int q = 0; q < 4; q++) dst[q] = o[q];
}

// prep: fused {transpose w1, transpose w2, gather x} by block range.
constexpr int NB_T1 = (DFF_DIM / 64) * (C_DIM / 64) * E_NUM;  // 8192
constexpr int NB_T2 = (C_DIM / 64) * (DFF_DIM / 64) * E_NUM;  // 8192
__global__ __launch_bounds__(256) void prep_kernel(
    const float* __restrict__ w1, unsigned short* __restrict__ w1b,
    const float* __restrict__ w2, unsigned short* __restrict__ w2b,
    const float* __restrict__ x, const int* __restrict__ rowtok,
    unsigned short* __restrict__ Xg) {
    __shared__ float tile[64][68];
    int b = blockIdx.x;
    if (b < NB_T1) {
        int bx = b & 63, by = (b >> 6) & 15, bz = b >> 10;
        transpose_body(w1 + (size_t)bz * C_DIM * DFF_DIM,
                       w1b + (size_t)bz * C_DIM * DFF_DIM,
                       C_DIM, DFF_DIM, by * 64, bx * 64, tile);
        return;
    }
    b -= NB_T1;
    if (b < NB_T2) {
        int bx = b & 15, by = (b >> 4) & 63, bz = b >> 10;
        transpose_body(w2 + (size_t)bz * C_DIM * DFF_DIM,
                       w2b + (size_t)bz * C_DIM * DFF_DIM,
                       DFF_DIM, C_DIM, by * 64, bx * 64, tile);
        return;
    }
    b -= NB_T2;
    // gather row b
    int tok = rowtok[b];
    const float4* src = (const float4*)(x + (size_t)tok * C_DIM);
    ushort4* dst = (ushort4*)(Xg + (size_t)b * C_DIM);
    int i = threadIdx.x;
    float4 v = src[i];
    ushort4 o;
    o.x = f2bf(v.x); o.y = f2bf(v.y); o.z = f2bf(v.z); o.w = f2bf(v.w);
    dst[i] = o;
}

// ---------------------------------------------------------------------------
// 256x256 GEMM (measured-best R8 structure), 512 thr = 8 waves (2M x 4N),
// BK=64, dbuf x2 (2 x 64KB LDS). Per K-tile: stage(t+1) (8 gload_lds), then
// 24 ds_read + 64 MFMA free-scheduled, ONE vmcnt(0) + ONE s_barrier.
// Swizzle: 128B rows, 16B slot s at phys s^(row&7) on gload SOURCE + read.
// Unified epilogue -> bf16 via LDS repack, coalesced 16B stores.
// MODE 1: relu(acc+bias) -> OutH.  MODE 2: acc + (z==0)*bias -> OutC{z}.
// ---------------------------------------------------------------------------
template <int KDIM, int KLEN, int NDIM, int MODE>
__global__ __launch_bounds__(512, 2) void gemm8_kernel(
    const unsigned short* __restrict__ A, const unsigned short* __restrict__ Bt,
    const float* __restrict__ bias, unsigned short* __restrict__ OutH,
    unsigned short* __restrict__ OutC0, unsigned short* __restrict__ OutC1,
    const int* __restrict__ meta) {
    extern __shared__ char ldsraw[];  // 131072 bytes

    int nwg = gridDim.x;
    int orig = blockIdx.x;
    int q = nwg >> 3, r8 = nwg & 7;
    int xcd = orig & 7, idx = orig >> 3;
    int wgid = (xcd < r8 ? xcd * (q + 1) : r8 * (q + 1) + (xcd - r8) * q) + idx;
    constexpr int NCT = NDIM / 256;
    int rowBase = (wgid / NCT) * 256;
    int colBase = (wgid % NCT) * 256;
    if (rowBase >= meta[24]) return;
    int e = 0;
#pragma unroll
    for (int i = 1; i < 8; i++)
        if (rowBase >= meta[16 + i]) e = i;
    int koff = blockIdx.z * KLEN;

    int tid = threadIdx.x;
    int wv = tid >> 6, lane = tid & 63;
    int wr = wv >> 2, wcol = wv & 3;  // 2M x 4N waves; wave output 128x64

    const unsigned short* Ab = A + (size_t)rowBase * KDIM + koff;
    const unsigned short* Bb = Bt + (size_t)e * NDIM * KDIM + (size_t)colBase * KDIM + koff;

    int rA = tid >> 3;
    int sSl = ((tid & 7) ^ (rA & 7)) * 8;
    const unsigned short* pA0 = Ab + (size_t)rA * KDIM + sSl;
    const unsigned short* pB0 = Bb + (size_t)rA * KDIM + sSl;

#define STAGEALL(tt) { \
        char* base_ = ldsraw + (((tt) & 1) << 16); \
        size_t kadd_ = (size_t)(tt) * 64; \
        _Pragma("unroll") for (int h_ = 0; h_ < 2; h_++) { \
            char* dA_ = base_ + h_ * 16384 + wv * 1024; \
            const unsigned short* sA_ = pA0 + (size_t)h_ * (128 * KDIM) + kadd_; \
            gload_lds16(sA_, dA_); \
            gload_lds16(sA_ + (size_t)64 * KDIM, dA_ + 8192); \
            char* dB_ = base_ + 32768 + h_ * 16384 + wv * 1024; \
            const unsigned short* sB_ = pB0 + (size_t)h_ * (128 * KDIM) + kadd_; \
            gload_lds16(sB_, dB_); \
            gload_lds16(sB_ + (size_t)64 * KDIM, dB_ + 8192); \
        } }

    int physk0 = (lane >> 4) ^ (lane & 7);
    int kdel = ((physk0 ^ 4) - physk0) * 16;  // +-64
    const char* aB0k0 = ldsraw + wr * 16384 + (lane & 15) * 128 + physk0 * 16;
    const char* aB0k1 = aB0k0 + kdel;
    const char* bB0k0 = ldsraw + 32768 + (wcol >> 1) * 16384 +
                        ((wcol & 1) * 64 + (lane & 15)) * 128 + physk0 * 16;
    const char* bB0k1 = bB0k0 + kdel;

    short8 afA[4][2], afB[4][2], bfA[2][2], bfB[2][2];
    f32x4 acc[8][4];
#pragma unroll
    for (int m = 0; m < 8; m++)
#pragma unroll
        for (int n = 0; n < 4; n++) acc[m][n] = f32x4{0.f, 0.f, 0.f, 0.f};

#define LDA(DST, K0, K1, MOFF) \
    _Pragma("unroll") for (int mm = 0; mm < 4; mm++) { \
        DST[mm][0] = *(const short8*)((K0) + ((MOFF) + mm) * 2048); \
        DST[mm][1] = *(const short8*)((K1) + ((MOFF) + mm) * 2048); }
#define LDB(DST, K0, K1, NOFF) \
    _Pragma("unroll") for (int nn = 0; nn < 2; nn++) { \
        DST[nn][0] = *(const short8*)((K0) + ((NOFF) + nn) * 2048); \
        DST[nn][1] = *(const short8*)((K1) + ((NOFF) + nn) * 2048); }
#define QUAD(AF, BF, MB, NB) \
    __builtin_amdgcn_s_setprio(1); \
    _Pragma("unroll") for (int kk = 0; kk < 2; kk++) \
    _Pragma("unroll") for (int mm = 0; mm < 4; mm++) \
    _Pragma("unroll") for (int nn = 0; nn < 2; nn++) \
        acc[(MB) + mm][(NB) + nn] = __builtin_amdgcn_mfma_f32_16x16x32_bf16( \
            AF[mm][kk], BF[nn][kk], acc[(MB) + mm][(NB) + nn], 0, 0, 0); \
    __builtin_amdgcn_s_setprio(0);
#define SB() __builtin_amdgcn_sched_barrier(0)

    constexpr int T = KLEN / 64;

    STAGEALL(0)
    SB(); asm volatile("s_waitcnt vmcnt(0)" ::: "memory"); SB();
    __builtin_amdgcn_s_barrier(); SB();

#pragma unroll 1
    for (int t = 0; t < T; ++t) {
        if (t + 1 < T) STAGEALL(t + 1)
        const char* ak0 = aB0k0 + ((t & 1) << 16);
        const char* ak1 = aB0k1 + ((t & 1) << 16);
        const char* bk0 = bB0k0 + ((t & 1) << 16);
        const char* bk1 = bB0k1 + ((t & 1) << 16);
        LDA(afA, ak0, ak1, 0)
        LDB(bfA, bk0, bk1, 0)
        LDB(bfB, bk0, bk1, 2)
        QUAD(afA, bfA, 0, 0)
        LDA(afB, ak0, ak1, 4)
        QUAD(afA, bfB, 0, 2)
        QUAD(afB, bfA, 4, 0)
        QUAD(afB, bfB, 4, 2)
        SB();
        asm volatile("s_waitcnt vmcnt(0)" ::: "memory");
        SB();
        __builtin_amdgcn_s_barrier();
        SB();
    }
#undef STAGEALL
#undef LDA
#undef LDB
#undef QUAD

    // Unified epilogue: bf16 via LDS repack with rr-XOR swizzle.
    float bv[4];
    bool addBias = (MODE == 1) || (blockIdx.z == 0);
#pragma unroll
    for (int n = 0; n < 4; n++)
        bv[n] = addBias ? bias[(size_t)e * NDIM + colBase + wcol * 64 + n * 16 + (lane & 15)]
                        : 0.f;
    unsigned short* OutP = (MODE == 1) ? OutH : (blockIdx.z == 0 ? OutC0 : OutC1);

    unsigned short* lds16 = (unsigned short*)ldsraw;
#pragma unroll
    for (int m = 0; m < 8; m++) {
#pragma unroll
        for (int n = 0; n < 4; n++) {
#pragma unroll
            for (int j = 0; j < 4; j++) {
                float v = acc[m][n][j] + bv[n];
                if (MODE == 1) v = fmaxf(v, 0.f);
                int rr = wr * 128 + m * 16 + (lane >> 4) * 4 + j;
                int cc = wcol * 64 + n * 16 + (lane & 15);
                lds16[rr * 256 + (cc ^ ((rr & 7) << 4))] = f2bf(v);
            }
        }
    }
    __syncthreads();
    {
        int row = tid >> 1, half = tid & 1;
        int xr = (row & 7) << 4;
#pragma unroll
        for (int i = 0; i < 16; i++) {
            int cs = half * 128 + i * 8;
            short8 val = *(const short8*)(lds16 + row * 256 + (cs ^ xr));
            *(short8*)(OutP + (size_t)(rowBase + row) * NDIM + colBase + cs) = val;
        }
    }
}

// out[t] = w0*(c0[p0]+c1[p0]) + w1*(c0[p1]+c1[p1])  (fixed order, deterministic)
__global__ void combine_kernel(const unsigned short* __restrict__ c0,
                               const unsigned short* __restrict__ c1,
                               const int2* __restrict__ tok_pos, const float2* __restrict__ tok_w,
                               float* __restrict__ out) {
    int t = blockIdx.x;
    int2 p = tok_pos[t];
    float2 w = tok_w[t];
    int i = threadIdx.x;  // 256 x 4 elems
    ushort4 a0 = ((const ushort4*)(c0 + (size_t)p.x * C_DIM))[i];
    ushort4 a1 = ((const ushort4*)(c1 + (size_t)p.x * C_DIM))[i];
    ushort4 b0 = ((const ushort4*)(c0 + (size_t)p.y * C_DIM))[i];
    ushort4 b1 = ((const ushort4*)(c1 + (size_t)p.y * C_DIM))[i];
    float4 r;
    r.x = w.x * (bf2f(a0.x) + bf2f(a1.x)) + w.y * (bf2f(b0.x) + bf2f(b1.x));
    r.y = w.x * (bf2f(a0.y) + bf2f(a1.y)) + w.y * (bf2f(b0.y) + bf2f(b1.y));
    r.z = w.x * (bf2f(a0.z) + bf2f(a1.z)) + w.y * (bf2f(b0.z) + bf2f(b1.z));
    r.w = w.x * (bf2f(a0.w) + bf2f(a1.w)) + w.y * (bf2f(b0.w) + bf2f(b1.w));
    ((float4*)(out + (size_t)t * C_DIM))[i] = r;
}

extern "C" void kernel_launch(void* const* d_in, const int* in_sizes, int n_in,
                              void* d_out, int out_size, void* d_ws, size_t ws_size,
                              hipStream_t stream) {
    (void)in_sizes; (void)n_in; (void)out_size; (void)ws_size;
    const float* x       = (const float*)d_in[0];
    const float* noise   = (const float*)d_in[1];
    const float* w_gate  = (const float*)d_in[2];
    const float* b_gate  = (const float*)d_in[3];
    const float* w_noise = (const float*)d_in[4];
    const float* b_noise = (const float*)d_in[5];
    const float* w1      = (const float*)d_in[6];
    const float* b1      = (const float*)d_in[7];
    const float* w2      = (const float*)d_in[8];
    const float* b2      = (const float*)d_in[9];
    float* out = (float*)d_out;

    char* w = (char*)d_ws;
    size_t off = 0;
    int* meta = (int*)(w + off); off += 256;
    float* wT = (float*)(w + off); off += 16 * C_DIM * 4;
    int2* tok_e = (int2*)(w + off); off += (size_t)NTOK * 8;
    float2* tok_w = (float2*)(w + off); off += (size_t)NTOK * 8;
    int2* tok_pos = (int2*)(w + off); off += (size_t)NTOK * 8;
    int* rowtok = (int*)(w + off); off += (size_t)MAXROWS * 4;
    unsigned short* H = (unsigned short*)(w + off); off += (size_t)MAXROWS * DFF_DIM * 2;
    unsigned short* w2b = (unsigned short*)(w + off); off += (size_t)E_NUM * C_DIM * DFF_DIM * 2;
    unsigned short* c0 = (unsigned short*)(w + off); off += (size_t)MAXROWS * C_DIM * 2;
    unsigned short* Xg = (unsigned short*)(w + off); off += (size_t)MAXROWS * C_DIM * 2;
    unsigned short* w1b = (unsigned short*)(w + off); off += (size_t)E_NUM * DFF_DIM * C_DIM * 2;
    // c1 aliases Xg (same size): Xg is dead once gemm1 has run, and is fully
    // rewritten by prep on every call (replay-safe).
    unsigned short* c1 = Xg;

    init_kernel<<<(MAXROWS + 255) / 256, 256, 0, stream>>>(meta, rowtok, w_gate, w_noise, wT);

    hipFuncSetAttribute((const void*)router_kernel,
                        hipFuncAttributeMaxDynamicSharedMemorySize, 65536);
    router_kernel<<<NTOK / 32, 256, 65536, stream>>>(x, noise, wT, b_gate, b_noise,
                                                     meta, tok_e, tok_w);
    offsets_kernel<<<1, 64, 0, stream>>>(meta);
    assign_kernel<<<NTOK / 256, 256, 0, stream>>>(meta, tok_e, tok_pos, rowtok);
    prep_kernel<<<NB_T1 + NB_T2 + MAXROWS, 256, 0, stream>>>(w1, w1b, w2, w2b, x, rowtok, Xg);

    hipFuncSetAttribute((const void*)gemm8_kernel<C_DIM, C_DIM, DFF_DIM, 1>,
                        hipFuncAttributeMaxDynamicSharedMemorySize, 131072);
    gemm8_kernel<C_DIM, C_DIM, DFF_DIM, 1>
        <<<dim3((MAXROWS / 256) * (DFF_DIM / 256), 1, 1), 512, 131072, stream>>>(
            Xg, w1b, b1, H, nullptr, nullptr, meta);

    hipFuncSetAttribute((const void*)gemm8_kernel<DFF_DIM, DFF_DIM / 2, C_DIM, 2>,
                        hipFuncAttributeMaxDynamicSharedMemorySize, 131072);
    gemm8_kernel<DFF_DIM, DFF_DIM / 2, C_DIM, 2>
        <<<dim3((MAXROWS / 256) * (C_DIM / 256), 1, 2), 512, 131072, stream>>>(
            H, w2b, b2, nullptr, c0, c1, meta);

    combine_kernel<<<NTOK, 256, 0, stream>>>(c0, c1, tok_pos, tok_w, out);
}